// Round 5
// baseline (16.498 us; speedup 1.0000x reference)
//
#include <hip/hip_runtime.h>

// WarpMesh R5: single fused kernel, 32x16-pixel tiles (288 blocks), 2 px/thread.
// Per block:
//  1. vertex stage: 256 threads normalize the 256 mesh vertices (NDC + UV)
//     into LDS — exactly the reference's per-vertex ops, so bit-identical.
//  2. bbox-only face pass (2 uniform rounds x 256 threads): bbox vs tile in
//     registers, ballot; after sync each SURVIVING thread builds its face
//     record (verts, inv_area, UVs, bbox) directly at its compacted slot —
//     ascending face order preserved (== reference argmax/first-hit).
//  3. per-pixel (x2 rows per thread): candidate scan with bbox prefilter
//     (guaranteed-miss skip), rounding-barriered edge test, bary UV, bilinear.
//
// Exactness: the inside test (w >= -1e-7 on normalized barycentrics) is
// sign-critical vs the numpy fp32 reference; every product feeding the edge
// functions / area goes through an asm rounding barrier (no FMA contraction),
// divisions are IEEE. Bbox margin 1e-4 NDC >> max boundary extension from
// tol + fp32 rounding (~7.5e-7 NDC), so neither tile-culling nor the
// per-pixel bbox prefilter can flip any inside bit.

#define NF_MAX 450
#define NP_MAX 256
#define WIMG 384
#define HIMG 384
#define TILE_W 32
#define TILE_H 16
#define MARGIN 1e-4f
#define FSTRIDE 17
// Record (17 floats): [0..5] v0x v0y v1x v1y v2x v2y, [6] inv_area,
// [7..12] uv0 uv1 uv2, [13..16] bxmin bymin bxmax bymax

__device__ __forceinline__ float fbar(float r) {
    asm volatile("" : "+v"(r));   // rounding/contraction barrier
    return r;
}
__device__ __forceinline__ float mulb(float a, float b) { return fbar(a * b); }

__global__ __launch_bounds__(256)
void wm_fused(const float* __restrict__ points,
              const float* __restrict__ uvp,
              const int*   __restrict__ faces,
              int nf, int np,
              const float* __restrict__ img,
              float* __restrict__ out)
{
    __shared__ float vx[NP_MAX], vy[NP_MAX], tux[NP_MAX], tuy[NP_MAX];
    __shared__ float flds[NF_MAX * FSTRIDE];
    __shared__ unsigned long long masks[8];

    const int tid = threadIdx.x;
    const float sc = (float)(383.0 / 384.0);  // (W-1)/W rounded to fp32

    // ---- vertex stage: coalesced loads, 4 IEEE divides per vertex ----
    if (tid < np) {
        float pxv = points[tid*2 + 0];
        float pyv = points[tid*2 + 1];
        vx[tid]  = fbar(fbar(fbar(pxv / 383.0f) * 2.0f - 1.0f) * sc);
        vy[tid]  = fbar(fbar(fbar(pyv / 383.0f) * 2.0f - 1.0f) * sc);
        tux[tid] = fbar(uvp[tid*2 + 0] / 383.0f);
        tuy[tid] = fbar(uvp[tid*2 + 1] / 383.0f);
    }
    __syncthreads();

    // ---- tile NDC bounds + margin ----
    const int lx = tid & 31, ly = tid >> 5;          // 32 x 8 thread layout
    const int c0 = blockIdx.x * TILE_W, r0 = blockIdx.y * TILE_H;
    const int col = c0 + lx;
    const int row0 = r0 + ly, row1 = r0 + ly + 8;    // 2 pixels per thread

    const float tx_lo = 2.0f * ((float)c0 + 0.5f)            / 384.0f - 1.0f - MARGIN;
    const float tx_hi = 2.0f * ((float)c0 + TILE_W - 0.5f)   / 384.0f - 1.0f + MARGIN;
    const float ty_lo = 2.0f * ((float)r0 + 0.5f)            / 384.0f - 1.0f - MARGIN;
    const float ty_hi = 2.0f * ((float)r0 + TILE_H - 0.5f)   / 384.0f - 1.0f + MARGIN;

    // ---- bbox-only face pass + ballot (2 uniform rounds) ----
    bool pred[2];
    int  fidx[2][3];
    #pragma unroll
    for (int r = 0; r < 2; ++r) {
        const int f = r * 256 + tid;
        bool p = false;
        if (f < nf) {
            int i0 = faces[f*3 + 0];
            int i1 = faces[f*3 + 1];
            int i2 = faces[f*3 + 2];
            fidx[r][0] = i0; fidx[r][1] = i1; fidx[r][2] = i2;

            float v0x = vx[i0], v0y = vy[i0];
            float v1x = vx[i1], v1y = vy[i1];
            float v2x = vx[i2], v2y = vy[i2];

            // area, no contraction (validity gate only here)
            float area = fbar(mulb(v1x - v0x, v2y - v0y)
                            - mulb(v1y - v0y, v2x - v0x));
            if (fabsf(area) >= 1e-8f) {
                float bxmin = fminf(fminf(v0x, v1x), v2x);
                float bymin = fminf(fminf(v0y, v1y), v2y);
                float bxmax = fmaxf(fmaxf(v0x, v1x), v2x);
                float bymax = fmaxf(fmaxf(v0y, v1y), v2y);
                p = (bxmin <= tx_hi) & (bxmax >= tx_lo)
                  & (bymin <= ty_hi) & (bymax >= ty_lo);
            }
        }
        pred[r] = p;
        unsigned long long m = __ballot(p);   // uniform: all lanes execute
        if ((tid & 63) == 0) masks[r * 4 + (tid >> 6)] = m;
    }
    __syncthreads();

    int ncand = 0;
    #pragma unroll
    for (int k = 0; k < 8; ++k) ncand += __popcll(masks[k]);

    // ---- surviving threads build compacted records (ascending face order) --
    const int lane = tid & 63;
    const unsigned long long below = (lane == 0) ? 0ULL : ((1ULL << lane) - 1ULL);
    #pragma unroll
    for (int r = 0; r < 2; ++r) {
        if (pred[r]) {
            int w = r * 4 + (tid >> 6);
            int pos = __popcll(masks[w] & below);
            for (int k = 0; k < w; ++k) pos += __popcll(masks[k]);

            int i0 = fidx[r][0], i1 = fidx[r][1], i2 = fidx[r][2];
            float v0x = vx[i0], v0y = vy[i0];
            float v1x = vx[i1], v1y = vy[i1];
            float v2x = vx[i2], v2y = vy[i2];

            float area = fbar(mulb(v1x - v0x, v2y - v0y)
                            - mulb(v1y - v0y, v2x - v0x));
            float inv_area = fbar(1.0f / area);   // valid guaranteed by pred

            float* o = &flds[pos * FSTRIDE];
            o[0] = v0x; o[1] = v0y; o[2] = v1x; o[3] = v1y;
            o[4] = v2x; o[5] = v2y; o[6] = inv_area;
            o[7]  = tux[i0]; o[8]  = tuy[i0];
            o[9]  = tux[i1]; o[10] = tuy[i1];
            o[11] = tux[i2]; o[12] = tuy[i2];
            o[13] = fminf(fminf(v0x, v1x), v2x);
            o[14] = fminf(fminf(v0y, v1y), v2y);
            o[15] = fmaxf(fmaxf(v0x, v1x), v2x);
            o[16] = fmaxf(fmaxf(v0y, v1y), v2y);
        }
    }
    __syncthreads();

    // ---- per-pixel raster, 2 pixels per thread ----
    const float px = fbar(fbar(2.0f * ((float)col + 0.5f) / 384.0f) - 1.0f);

    #pragma unroll
    for (int sp = 0; sp < 2; ++sp) {
        const int row = sp ? row1 : row0;
        const float py = fbar(fbar(2.0f * ((float)row + 0.5f) / 384.0f) - 1.0f);

        int   hitoff = -1;
        float b0 = 0.0f, b1 = 0.0f, b2 = 0.0f;

        for (int i = 0; i < ncand; ++i) {
            const float* fd = &flds[i * FSTRIDE];  // broadcast LDS reads
            // bbox prefilter: outside bbox -> guaranteed miss (margin arg)
            if (px < fd[13] - MARGIN || px > fd[15] + MARGIN ||
                py < fd[14] - MARGIN || py > fd[16] + MARGIN) continue;

            const float v0x = fd[0], v0y = fd[1];
            const float v1x = fd[2], v1y = fd[3];
            const float v2x = fd[4], v2y = fd[5];
            const float ia  = fd[6];

            // edge_fn(a,b) = (bx-ax)*(py-ay) - (by-ay)*(px-ax), no contraction
            float e0 = fbar(mulb(v2x - v1x, py - v1y) - mulb(v2y - v1y, px - v1x));
            float e1 = fbar(mulb(v0x - v2x, py - v2y) - mulb(v0y - v2y, px - v2x));
            float e2 = fbar(mulb(v1x - v0x, py - v0y) - mulb(v1y - v0y, px - v0x));

            float w0 = mulb(e0, ia);
            float w1 = mulb(e1, ia);
            float w2 = mulb(e2, ia);

            if (w0 >= -1e-7f && w1 >= -1e-7f && w2 >= -1e-7f) {
                hitoff = i * FSTRIDE; b0 = w0; b1 = w1; b2 = w2;
                break;  // ascending order -> first hit == argmax(inside)
            }
        }

        float c0f = 0.0f, c1f = 0.0f, c2f = 0.0f;
        if (hitoff >= 0) {
            const float* fd = &flds[hitoff];
            float ux = b0 * fd[7] + b1 * fd[9]  + b2 * fd[11];
            float uy = b0 * fd[8] + b1 * fd[10] + b2 * fd[12];

            float x = fminf(fmaxf(ux * 383.0f, 0.0f), 383.0f);
            float y = fminf(fmaxf(uy * 383.0f, 0.0f), 383.0f);
            int x0 = (int)floorf(x);
            int y0 = (int)floorf(y);
            int x1 = min(x0 + 1, 383);
            int y1 = min(y0 + 1, 383);
            float fx = x - (float)x0;
            float fy = y - (float)y0;

            const float* p00 = &img[(y0 * WIMG + x0) * 3];
            const float* p10 = &img[(y0 * WIMG + x1) * 3];
            const float* p01 = &img[(y1 * WIMG + x0) * 3];
            const float* p11 = &img[(y1 * WIMG + x1) * 3];

            float w00 = (1.0f - fx) * (1.0f - fy);
            float w10 = fx * (1.0f - fy);
            float w01 = (1.0f - fx) * fy;
            float w11 = fx * fy;

            c0f = p00[0]*w00 + p10[0]*w10 + p01[0]*w01 + p11[0]*w11;
            c1f = p00[1]*w00 + p10[1]*w10 + p01[1]*w01 + p11[1]*w11;
            c2f = p00[2]*w00 + p10[2]*w10 + p01[2]*w01 + p11[2]*w11;
        }

        const int p = row * WIMG + col;
        out[p * 3 + 0] = c0f;
        out[p * 3 + 1] = c1f;
        out[p * 3 + 2] = c2f;
    }
}

extern "C" void kernel_launch(void* const* d_in, const int* in_sizes, int n_in,
                              void* d_out, int out_size, void* d_ws, size_t ws_size,
                              hipStream_t stream) {
    const float* points = (const float*)d_in[0];
    const float* uvp    = (const float*)d_in[1];
    const float* img    = (const float*)d_in[2];
    const int*   faces  = (const int*)d_in[3];

    int nf = in_sizes[3] / 3;
    if (nf > NF_MAX) nf = NF_MAX;
    int np = in_sizes[0] / 2;
    if (np > NP_MAX) np = NP_MAX;

    hipLaunchKernelGGL(wm_fused, dim3(WIMG / TILE_W, HIMG / TILE_H), dim3(256),
                       0, stream, points, uvp, faces, nf, np, img, (float*)d_out);
}

// Round 6
// 10.572 us; speedup vs baseline: 1.5606x; 1.5606x over previous
//
#include <hip/hip_runtime.h>

// WarpMesh R6: R4 structure (16x16 tiles, 576 blocks, 1 px/thread — measured
// best) + candidate-only record build + float4 LDS record reads.
// Per block:
//  1. vertex stage: 256 threads normalize the 256 mesh vertices (NDC + UV)
//     into LDS — exactly the reference's per-vertex ops, bit-identical.
//  2. bbox-only face pass (2 uniform rounds x 256 threads): validity + bbox
//     vs tile in registers, ballot; after sync each SURVIVING thread builds
//     its record (verts, inv_area, UVs) at its compacted slot, stride 20
//     (16B-aligned) — ascending face order == reference argmax/first-hit.
//  3. per-pixel: first-hit scan over ~12 candidates via 2x ds_read_b128
//     broadcast, rounding-barriered edge test, bary UV, bilinear sample.
//
// R5 lesson: 2px/thread halved wave-level parallelism (latency-bound kernel)
// and the per-pixel bbox prefilter was lane-divergent (no wave-level saving)
// — both reverted here.
//
// Exactness: the inside test (w >= -1e-7 on normalized barycentrics) is
// sign-critical vs the numpy fp32 reference; every product feeding the edge
// functions / area goes through an asm rounding barrier (no FMA contraction),
// divisions are IEEE. Bbox margin 1e-4 NDC >> max boundary extension from
// tol + fp32 rounding (~7.5e-7 NDC), so tile-culling cannot flip any
// inside bit.

#define NF_MAX 450
#define NP_MAX 256
#define WIMG 384
#define HIMG 384
#define MARGIN 1e-4f
#define FSTRIDE 20   // floats; 80B = 16B-aligned records for float4 reads
// Record (14 used floats @ stride 20):
// [0..3] v0x v0y v1x v1y | [4..6] v2x v2y inv_area |
// [8..11] uv0x uv0y uv1x uv1y | [12..13] uv2x uv2y

__device__ __forceinline__ float fbar(float r) {
    asm volatile("" : "+v"(r));   // rounding/contraction barrier
    return r;
}
__device__ __forceinline__ float mulb(float a, float b) { return fbar(a * b); }

__global__ __launch_bounds__(256)
void wm_fused(const float* __restrict__ points,
              const float* __restrict__ uvp,
              const int*   __restrict__ faces,
              int nf, int np,
              const float* __restrict__ img,
              float* __restrict__ out)
{
    __shared__ float vx[NP_MAX], vy[NP_MAX], tux[NP_MAX], tuy[NP_MAX];
    __shared__ __align__(16) float flds[NF_MAX * FSTRIDE];
    __shared__ unsigned long long masks[8];

    const int tid = threadIdx.x;
    const float sc = (float)(383.0 / 384.0);  // (W-1)/W rounded to fp32

    // ---- vertex stage: coalesced loads, 4 IEEE divides per vertex ----
    if (tid < np) {
        float pxv = points[tid*2 + 0];
        float pyv = points[tid*2 + 1];
        vx[tid]  = fbar(fbar(fbar(pxv / 383.0f) * 2.0f - 1.0f) * sc);
        vy[tid]  = fbar(fbar(fbar(pyv / 383.0f) * 2.0f - 1.0f) * sc);
        tux[tid] = fbar(uvp[tid*2 + 0] / 383.0f);
        tuy[tid] = fbar(uvp[tid*2 + 1] / 383.0f);
    }
    __syncthreads();

    // ---- tile NDC bounds + margin ----
    const int lx = tid & 15, ly = tid >> 4;
    const int c0 = blockIdx.x * 16, r0 = blockIdx.y * 16;
    const int col = c0 + lx, row = r0 + ly;

    const float tx_lo = 2.0f * ((float)c0 + 0.5f)  / 384.0f - 1.0f - MARGIN;
    const float tx_hi = 2.0f * ((float)c0 + 15.5f) / 384.0f - 1.0f + MARGIN;
    const float ty_lo = 2.0f * ((float)r0 + 0.5f)  / 384.0f - 1.0f - MARGIN;
    const float ty_hi = 2.0f * ((float)r0 + 15.5f) / 384.0f - 1.0f + MARGIN;

    // ---- bbox-only face pass + ballot (2 uniform rounds) ----
    bool pred[2];
    int  fidx[2][3];
    #pragma unroll
    for (int r = 0; r < 2; ++r) {
        const int f = r * 256 + tid;
        bool p = false;
        if (f < nf) {
            int i0 = faces[f*3 + 0];
            int i1 = faces[f*3 + 1];
            int i2 = faces[f*3 + 2];
            fidx[r][0] = i0; fidx[r][1] = i1; fidx[r][2] = i2;

            float v0x = vx[i0], v0y = vy[i0];
            float v1x = vx[i1], v1y = vy[i1];
            float v2x = vx[i2], v2y = vy[i2];

            // area, no contraction (validity gate only here)
            float area = fbar(mulb(v1x - v0x, v2y - v0y)
                            - mulb(v1y - v0y, v2x - v0x));
            if (fabsf(area) >= 1e-8f) {
                float bxmin = fminf(fminf(v0x, v1x), v2x);
                float bymin = fminf(fminf(v0y, v1y), v2y);
                float bxmax = fmaxf(fmaxf(v0x, v1x), v2x);
                float bymax = fmaxf(fmaxf(v0y, v1y), v2y);
                p = (bxmin <= tx_hi) & (bxmax >= tx_lo)
                  & (bymin <= ty_hi) & (bymax >= ty_lo);
            }
        }
        pred[r] = p;
        unsigned long long m = __ballot(p);   // uniform: all lanes execute
        if ((tid & 63) == 0) masks[r * 4 + (tid >> 6)] = m;
    }
    __syncthreads();

    int ncand = 0;
    #pragma unroll
    for (int k = 0; k < 8; ++k) ncand += __popcll(masks[k]);

    // ---- survivors build compacted records (ascending face order) ----
    const int lane = tid & 63;
    const unsigned long long below = (lane == 0) ? 0ULL : ((1ULL << lane) - 1ULL);
    #pragma unroll
    for (int r = 0; r < 2; ++r) {
        if (pred[r]) {
            int w = r * 4 + (tid >> 6);
            int pos = __popcll(masks[w] & below);
            for (int k = 0; k < w; ++k) pos += __popcll(masks[k]);

            int i0 = fidx[r][0], i1 = fidx[r][1], i2 = fidx[r][2];
            float v0x = vx[i0], v0y = vy[i0];
            float v1x = vx[i1], v1y = vy[i1];
            float v2x = vx[i2], v2y = vy[i2];

            float area = fbar(mulb(v1x - v0x, v2y - v0y)
                            - mulb(v1y - v0y, v2x - v0x));
            float inv_area = fbar(1.0f / area);   // validity guaranteed by pred

            float* o = &flds[pos * FSTRIDE];
            o[0] = v0x; o[1] = v0y; o[2] = v1x; o[3] = v1y;
            o[4] = v2x; o[5] = v2y; o[6] = inv_area;
            o[8]  = tux[i0]; o[9]  = tuy[i0];
            o[10] = tux[i1]; o[11] = tuy[i1];
            o[12] = tux[i2]; o[13] = tuy[i2];
        }
    }
    __syncthreads();

    // ---- per-pixel raster over candidates (ascending face order) ----
    const float px = fbar(fbar(2.0f * ((float)col + 0.5f) / 384.0f) - 1.0f);
    const float py = fbar(fbar(2.0f * ((float)row + 0.5f) / 384.0f) - 1.0f);

    int   hitoff = -1;
    float b0 = 0.0f, b1 = 0.0f, b2 = 0.0f;

    for (int i = 0; i < ncand; ++i) {
        // two broadcast ds_read_b128 per candidate
        const float4 A = *(const float4*)&flds[i * FSTRIDE];      // v0x v0y v1x v1y
        const float4 B = *(const float4*)&flds[i * FSTRIDE + 4];  // v2x v2y ia pad
        const float v0x = A.x, v0y = A.y;
        const float v1x = A.z, v1y = A.w;
        const float v2x = B.x, v2y = B.y;
        const float ia  = B.z;

        // edge_fn(a,b) = (bx-ax)*(py-ay) - (by-ay)*(px-ax), no contraction
        float e0 = fbar(mulb(v2x - v1x, py - v1y) - mulb(v2y - v1y, px - v1x));
        float e1 = fbar(mulb(v0x - v2x, py - v2y) - mulb(v0y - v2y, px - v2x));
        float e2 = fbar(mulb(v1x - v0x, py - v0y) - mulb(v1y - v0y, px - v0x));

        float w0 = mulb(e0, ia);
        float w1 = mulb(e1, ia);
        float w2 = mulb(e2, ia);

        if (w0 >= -1e-7f && w1 >= -1e-7f && w2 >= -1e-7f) {
            hitoff = i * FSTRIDE; b0 = w0; b1 = w1; b2 = w2;
            break;  // ascending order -> first hit == argmax(inside)
        }
    }

    float c0f = 0.0f, c1f = 0.0f, c2f = 0.0f;
    if (hitoff >= 0) {
        const float4 U0 = *(const float4*)&flds[hitoff + 8];   // uv0x uv0y uv1x uv1y
        const float ux = b0 * U0.x + b1 * U0.z + b2 * flds[hitoff + 12];
        const float uy = b0 * U0.y + b1 * U0.w + b2 * flds[hitoff + 13];

        float x = fminf(fmaxf(ux * 383.0f, 0.0f), 383.0f);
        float y = fminf(fmaxf(uy * 383.0f, 0.0f), 383.0f);
        int x0 = (int)floorf(x);
        int y0 = (int)floorf(y);
        int x1 = min(x0 + 1, 383);
        int y1 = min(y0 + 1, 383);
        float fx = x - (float)x0;
        float fy = y - (float)y0;

        const float* p00 = &img[(y0 * WIMG + x0) * 3];
        const float* p10 = &img[(y0 * WIMG + x1) * 3];
        const float* p01 = &img[(y1 * WIMG + x0) * 3];
        const float* p11 = &img[(y1 * WIMG + x1) * 3];

        float w00 = (1.0f - fx) * (1.0f - fy);
        float w10 = fx * (1.0f - fy);
        float w01 = (1.0f - fx) * fy;
        float w11 = fx * fy;

        c0f = p00[0]*w00 + p10[0]*w10 + p01[0]*w01 + p11[0]*w11;
        c1f = p00[1]*w00 + p10[1]*w10 + p01[1]*w01 + p11[1]*w11;
        c2f = p00[2]*w00 + p10[2]*w10 + p01[2]*w01 + p11[2]*w11;
    }

    const int p = row * WIMG + col;
    out[p * 3 + 0] = c0f;
    out[p * 3 + 1] = c1f;
    out[p * 3 + 2] = c2f;
}

extern "C" void kernel_launch(void* const* d_in, const int* in_sizes, int n_in,
                              void* d_out, int out_size, void* d_ws, size_t ws_size,
                              hipStream_t stream) {
    const float* points = (const float*)d_in[0];
    const float* uvp    = (const float*)d_in[1];
    const float* img    = (const float*)d_in[2];
    const int*   faces  = (const int*)d_in[3];

    int nf = in_sizes[3] / 3;
    if (nf > NF_MAX) nf = NF_MAX;
    int np = in_sizes[0] / 2;
    if (np > NP_MAX) np = NP_MAX;

    hipLaunchKernelGGL(wm_fused, dim3(WIMG / 16, HIMG / 16), dim3(256),
                       0, stream, points, uvp, faces, nf, np, img, (float*)d_out);
}

// Round 7
// 10.416 us; speedup vs baseline: 1.5839x; 1.0149x over previous
//
#include <hip/hip_runtime.h>

// WarpMesh R7: R6 (measured best: 16x16 tiles, 576 blocks, 1 px/thread,
// candidate-only record build, float4 LDS reads) + entry-point prefetch of
// the face-index gathers: the faces[] loads for both ballot rounds are
// issued BEFORE the vertex stage and first barrier, so their global-load
// latency overlaps prep instead of serializing after the barrier (hipcc
// will not hoist global loads across s_barrier itself).
//
// Exactness: the inside test (w >= -1e-7 on normalized barycentrics) is
// sign-critical vs the numpy fp32 reference; every product feeding the edge
// functions / area goes through an asm rounding barrier (no FMA contraction),
// divisions are IEEE. Bbox margin 1e-4 NDC >> max boundary extension from
// tol + fp32 rounding (~7.5e-7 NDC), so tile-culling cannot flip any
// inside bit.

#define NF_MAX 450
#define NP_MAX 256
#define WIMG 384
#define HIMG 384
#define MARGIN 1e-4f
#define FSTRIDE 20   // floats; 80B = 16B-aligned records for float4 reads
// Record (14 used floats @ stride 20):
// [0..3] v0x v0y v1x v1y | [4..6] v2x v2y inv_area |
// [8..11] uv0x uv0y uv1x uv1y | [12..13] uv2x uv2y

__device__ __forceinline__ float fbar(float r) {
    asm volatile("" : "+v"(r));   // rounding/contraction barrier
    return r;
}
__device__ __forceinline__ float mulb(float a, float b) { return fbar(a * b); }

__global__ __launch_bounds__(256)
void wm_fused(const float* __restrict__ points,
              const float* __restrict__ uvp,
              const int*   __restrict__ faces,
              int nf, int np,
              const float* __restrict__ img,
              float* __restrict__ out)
{
    __shared__ float vx[NP_MAX], vy[NP_MAX], tux[NP_MAX], tuy[NP_MAX];
    __shared__ __align__(16) float flds[NF_MAX * FSTRIDE];
    __shared__ unsigned long long masks[8];

    const int tid = threadIdx.x;
    const float sc = (float)(383.0 / 384.0);  // (W-1)/W rounded to fp32

    // ---- prefetch: dependency-free face-index gathers for both rounds ----
    int fidx[2][3];
    #pragma unroll
    for (int r = 0; r < 2; ++r) {
        const int f = r * 256 + tid;
        if (f < nf) {
            fidx[r][0] = faces[f*3 + 0];
            fidx[r][1] = faces[f*3 + 1];
            fidx[r][2] = faces[f*3 + 2];
        } else {
            fidx[r][0] = fidx[r][1] = fidx[r][2] = 0;
        }
    }

    // ---- vertex stage: coalesced loads, 4 IEEE divides per vertex ----
    if (tid < np) {
        float pxv = points[tid*2 + 0];
        float pyv = points[tid*2 + 1];
        vx[tid]  = fbar(fbar(fbar(pxv / 383.0f) * 2.0f - 1.0f) * sc);
        vy[tid]  = fbar(fbar(fbar(pyv / 383.0f) * 2.0f - 1.0f) * sc);
        tux[tid] = fbar(uvp[tid*2 + 0] / 383.0f);
        tuy[tid] = fbar(uvp[tid*2 + 1] / 383.0f);
    }
    __syncthreads();

    // ---- tile NDC bounds + margin ----
    const int lx = tid & 15, ly = tid >> 4;
    const int c0 = blockIdx.x * 16, r0 = blockIdx.y * 16;
    const int col = c0 + lx, row = r0 + ly;

    const float tx_lo = 2.0f * ((float)c0 + 0.5f)  / 384.0f - 1.0f - MARGIN;
    const float tx_hi = 2.0f * ((float)c0 + 15.5f) / 384.0f - 1.0f + MARGIN;
    const float ty_lo = 2.0f * ((float)r0 + 0.5f)  / 384.0f - 1.0f - MARGIN;
    const float ty_hi = 2.0f * ((float)r0 + 15.5f) / 384.0f - 1.0f + MARGIN;

    // ---- bbox-only face pass + ballot (2 uniform rounds) ----
    bool pred[2];
    #pragma unroll
    for (int r = 0; r < 2; ++r) {
        const int f = r * 256 + tid;
        bool p = false;
        if (f < nf) {
            int i0 = fidx[r][0], i1 = fidx[r][1], i2 = fidx[r][2];

            float v0x = vx[i0], v0y = vy[i0];
            float v1x = vx[i1], v1y = vy[i1];
            float v2x = vx[i2], v2y = vy[i2];

            // area, no contraction (validity gate only here)
            float area = fbar(mulb(v1x - v0x, v2y - v0y)
                            - mulb(v1y - v0y, v2x - v0x));
            if (fabsf(area) >= 1e-8f) {
                float bxmin = fminf(fminf(v0x, v1x), v2x);
                float bymin = fminf(fminf(v0y, v1y), v2y);
                float bxmax = fmaxf(fmaxf(v0x, v1x), v2x);
                float bymax = fmaxf(fmaxf(v0y, v1y), v2y);
                p = (bxmin <= tx_hi) & (bxmax >= tx_lo)
                  & (bymin <= ty_hi) & (bymax >= ty_lo);
            }
        }
        pred[r] = p;
        unsigned long long m = __ballot(p);   // uniform: all lanes execute
        if ((tid & 63) == 0) masks[r * 4 + (tid >> 6)] = m;
    }
    __syncthreads();

    int ncand = 0;
    #pragma unroll
    for (int k = 0; k < 8; ++k) ncand += __popcll(masks[k]);

    // ---- survivors build compacted records (ascending face order) ----
    const int lane = tid & 63;
    const unsigned long long below = (lane == 0) ? 0ULL : ((1ULL << lane) - 1ULL);
    #pragma unroll
    for (int r = 0; r < 2; ++r) {
        if (pred[r]) {
            int w = r * 4 + (tid >> 6);
            int pos = __popcll(masks[w] & below);
            for (int k = 0; k < w; ++k) pos += __popcll(masks[k]);

            int i0 = fidx[r][0], i1 = fidx[r][1], i2 = fidx[r][2];
            float v0x = vx[i0], v0y = vy[i0];
            float v1x = vx[i1], v1y = vy[i1];
            float v2x = vx[i2], v2y = vy[i2];

            float area = fbar(mulb(v1x - v0x, v2y - v0y)
                            - mulb(v1y - v0y, v2x - v0x));
            float inv_area = fbar(1.0f / area);   // validity guaranteed by pred

            float* o = &flds[pos * FSTRIDE];
            o[0] = v0x; o[1] = v0y; o[2] = v1x; o[3] = v1y;
            o[4] = v2x; o[5] = v2y; o[6] = inv_area;
            o[8]  = tux[i0]; o[9]  = tuy[i0];
            o[10] = tux[i1]; o[11] = tuy[i1];
            o[12] = tux[i2]; o[13] = tuy[i2];
        }
    }
    __syncthreads();

    // ---- per-pixel raster over candidates (ascending face order) ----
    const float px = fbar(fbar(2.0f * ((float)col + 0.5f) / 384.0f) - 1.0f);
    const float py = fbar(fbar(2.0f * ((float)row + 0.5f) / 384.0f) - 1.0f);

    int   hitoff = -1;
    float b0 = 0.0f, b1 = 0.0f, b2 = 0.0f;

    for (int i = 0; i < ncand; ++i) {
        // two broadcast ds_read_b128 per candidate
        const float4 A = *(const float4*)&flds[i * FSTRIDE];      // v0x v0y v1x v1y
        const float4 B = *(const float4*)&flds[i * FSTRIDE + 4];  // v2x v2y ia pad
        const float v0x = A.x, v0y = A.y;
        const float v1x = A.z, v1y = A.w;
        const float v2x = B.x, v2y = B.y;
        const float ia  = B.z;

        // edge_fn(a,b) = (bx-ax)*(py-ay) - (by-ay)*(px-ax), no contraction
        float e0 = fbar(mulb(v2x - v1x, py - v1y) - mulb(v2y - v1y, px - v1x));
        float e1 = fbar(mulb(v0x - v2x, py - v2y) - mulb(v0y - v2y, px - v2x));
        float e2 = fbar(mulb(v1x - v0x, py - v0y) - mulb(v1y - v0y, px - v0x));

        float w0 = mulb(e0, ia);
        float w1 = mulb(e1, ia);
        float w2 = mulb(e2, ia);

        if (w0 >= -1e-7f && w1 >= -1e-7f && w2 >= -1e-7f) {
            hitoff = i * FSTRIDE; b0 = w0; b1 = w1; b2 = w2;
            break;  // ascending order -> first hit == argmax(inside)
        }
    }

    float c0f = 0.0f, c1f = 0.0f, c2f = 0.0f;
    if (hitoff >= 0) {
        const float4 U0 = *(const float4*)&flds[hitoff + 8];   // uv0x uv0y uv1x uv1y
        const float ux = b0 * U0.x + b1 * U0.z + b2 * flds[hitoff + 12];
        const float uy = b0 * U0.y + b1 * U0.w + b2 * flds[hitoff + 13];

        float x = fminf(fmaxf(ux * 383.0f, 0.0f), 383.0f);
        float y = fminf(fmaxf(uy * 383.0f, 0.0f), 383.0f);
        int x0 = (int)floorf(x);
        int y0 = (int)floorf(y);
        int x1 = min(x0 + 1, 383);
        int y1 = min(y0 + 1, 383);
        float fx = x - (float)x0;
        float fy = y - (float)y0;

        const float* p00 = &img[(y0 * WIMG + x0) * 3];
        const float* p10 = &img[(y0 * WIMG + x1) * 3];
        const float* p01 = &img[(y1 * WIMG + x0) * 3];
        const float* p11 = &img[(y1 * WIMG + x1) * 3];

        float w00 = (1.0f - fx) * (1.0f - fy);
        float w10 = fx * (1.0f - fy);
        float w01 = (1.0f - fx) * fy;
        float w11 = fx * fy;

        c0f = p00[0]*w00 + p10[0]*w10 + p01[0]*w01 + p11[0]*w11;
        c1f = p00[1]*w00 + p10[1]*w10 + p01[1]*w01 + p11[1]*w11;
        c2f = p00[2]*w00 + p10[2]*w10 + p01[2]*w01 + p11[2]*w11;
    }

    const int p = row * WIMG + col;
    out[p * 3 + 0] = c0f;
    out[p * 3 + 1] = c1f;
    out[p * 3 + 2] = c2f;
}

extern "C" void kernel_launch(void* const* d_in, const int* in_sizes, int n_in,
                              void* d_out, int out_size, void* d_ws, size_t ws_size,
                              hipStream_t stream) {
    const float* points = (const float*)d_in[0];
    const float* uvp    = (const float*)d_in[1];
    const float* img    = (const float*)d_in[2];
    const int*   faces  = (const int*)d_in[3];

    int nf = in_sizes[3] / 3;
    if (nf > NF_MAX) nf = NF_MAX;
    int np = in_sizes[0] / 2;
    if (np > NP_MAX) np = NP_MAX;

    hipLaunchKernelGGL(wm_fused, dim3(WIMG / 16, HIMG / 16), dim3(256),
                       0, stream, points, uvp, faces, nf, np, img, (float*)d_out);
}